// Round 5
// baseline (1611.948 us; speedup 1.0000x reference)
//
#include <hip/hip_runtime.h>

typedef unsigned short u16;
typedef __attribute__((ext_vector_type(8))) short bf16x8;   // 8 bf16 (4 VGPR) MFMA frag
typedef __attribute__((ext_vector_type(8))) unsigned short us8;
typedef __attribute__((ext_vector_type(4))) unsigned short us4;
typedef __attribute__((ext_vector_type(4))) float f32x4;

#define SEQ    1024
#define TOK    2048           // B*S
#define HID    1024
#define NLAYER 6
#define NHEAD  16
#define HDIM   64
#define QKV3   3072
#define INTER  2730
#define IPAD   2816
#define VOCAB  32000
#define LN_EPS 1e-5f

__device__ __forceinline__ u16 f2bf(float f) {
  unsigned u = __float_as_uint(f);
  return (u16)((u + 0x7fffu + ((u >> 16) & 1u)) >> 16);   // RNE
}
__device__ __forceinline__ float bf2f(u16 u) {
  return __uint_as_float(((unsigned)u) << 16);
}

__device__ __forceinline__ void gl_lds16(const void* g, void* l) {
  __builtin_amdgcn_global_load_lds(
      (const __attribute__((address_space(1))) void*)g,
      (__attribute__((address_space(3))) void*)l, 16, 0, 0);
}

// ---------------- embedding: h = tok_emb[id] + pos_emb[s] (f32) ----------------
__global__ __launch_bounds__(256) void embed_kernel(
    const int* __restrict__ ids, const float* __restrict__ tok,
    const float* __restrict__ pos, float* __restrict__ h)
{
  int t = blockIdx.x;
  int s = t & (SEQ - 1);
  int id = ids[t];
  int c = threadIdx.x * 4;
  float4 tv = *(const float4*)(tok + (long)id * HID + c);
  float4 pv = *(const float4*)(pos + (long)s * HID + c);
  float4 o;
  o.x = tv.x + pv.x; o.y = tv.y + pv.y; o.z = tv.z + pv.z; o.w = tv.w + pv.w;
  *(float4*)(h + (long)t * HID + c) = o;
}

// ---------------- layernorm: f32 in -> bf16 out ----------------
__global__ __launch_bounds__(256) void ln_kernel(
    const float* __restrict__ h, const float* __restrict__ w,
    const float* __restrict__ b, u16* __restrict__ out)
{
  int t = blockIdx.x;
  int tid = threadIdx.x;
  int lane = tid & 63, wid = tid >> 6;
  float4 v = *(const float4*)(h + (long)t * HID + tid * 4);
  float s1 = v.x + v.y + v.z + v.w;
  float s2 = v.x * v.x + v.y * v.y + v.z * v.z + v.w * v.w;
#pragma unroll
  for (int o = 32; o > 0; o >>= 1) { s1 += __shfl_down(s1, o); s2 += __shfl_down(s2, o); }
  __shared__ float r1[4], r2[4];
  if (lane == 0) { r1[wid] = s1; r2[wid] = s2; }
  __syncthreads();
  float t1 = r1[0] + r1[1] + r1[2] + r1[3];
  float t2 = r2[0] + r2[1] + r2[2] + r2[3];
  float mu = t1 * (1.f / HID);
  float var = t2 * (1.f / HID) - mu * mu;
  float rs = rsqrtf(var + LN_EPS);
  float4 wv = *(const float4*)(w + tid * 4);
  float4 bv = *(const float4*)(b + tid * 4);
  us4 o4;
  o4[0] = f2bf((v.x - mu) * rs * wv.x + bv.x);
  o4[1] = f2bf((v.y - mu) * rs * wv.y + bv.y);
  o4[2] = f2bf((v.z - mu) * rs * wv.z + bv.z);
  o4[3] = f2bf((v.w - mu) * rs * wv.w + bv.w);
  *(us4*)(out + (long)t * HID + tid * 4) = o4;
}

// ---------------- f32 -> bf16 weight convert with zero padding ----------------
__global__ __launch_bounds__(256) void cvt_kernel(
    const float* __restrict__ src, u16* __restrict__ dst,
    int N, int K, int Kpad, long total8)
{
  long i = (long)blockIdx.x * 256 + threadIdx.x;
  if (i >= total8) return;
  int kp8 = Kpad >> 3;
  int n = (int)(i / kp8);
  int kc = (int)(i % kp8);
  us8 o;
#pragma unroll
  for (int j = 0; j < 8; ++j) {
    int k = kc * 8 + j;
    float v = (n < N && k < K) ? src[(long)n * K + k] : 0.f;
    o[j] = f2bf(v);
  }
  *(us8*)(dst + i * 8) = o;
}

// -------- interleaved gate/up convert: dst row 2g = gate[g], 2g+1 = up[g] --------
__global__ __launch_bounds__(256) void cvt2i_kernel(
    const float* __restrict__ gate, const float* __restrict__ up,
    u16* __restrict__ dst, long total8)
{
  long i = (long)blockIdx.x * 256 + threadIdx.x;   // 5632*128
  if (i >= total8) return;
  int n  = (int)(i >> 7);        // interleaved row 0..5631
  int kc = (int)(i & 127);
  int g  = n >> 1;
  const float* src = (n & 1) ? up : gate;
  us8 o;
#pragma unroll
  for (int j = 0; j < 8; ++j) {
    int k = kc * 8 + j;
    float v = (g < INTER) ? src[(long)g * HID + k] : 0.f;
    o[j] = f2bf(v);
  }
  *(us8*)(dst + i * 8) = o;
}

// ---------------- V transpose: vT[z][d][k] = qkv[b][k][2048 + h*64 + d] ----------------
__global__ __launch_bounds__(256) void vtrans_kernel(
    const u16* __restrict__ qkv, u16* __restrict__ vT)
{
  int gid = blockIdx.x * 256 + threadIdx.x;     // 32*64*128 total
  int d  = gid & 63;
  int kc = (gid >> 6) & 127;
  int z  = gid >> 13;                           // b*16+h
  int b = z >> 4, hh = z & 15;
  const u16* src = qkv + (long)b * SEQ * QKV3 + 2048 + hh * 64 + d;
  us8 v;
#pragma unroll
  for (int j = 0; j < 8; ++j) v[j] = src[(long)(kc * 8 + j) * QKV3];
  *(us8*)(vT + (long)z * 65536 + (long)d * 1024 + kc * 8) = v;
}

// ---------------- fused flash attention (see r4) ----------------
__global__ __launch_bounds__(256, 2) void attn_kernel(
    const u16* __restrict__ qkv, const u16* __restrict__ vT,
    u16* __restrict__ ctx)
{
  __shared__ u16 Ks[8][128][8];     // [d-grp][kseq][8d]  16 KB
  __shared__ u16 Vs[16][64][8];     // [k-grp][d][8k]     16 KB
  __shared__ u16 Ps[4][32 * 128];   // per-wave P tile    32 KB

  const int tid  = threadIdx.x;
  const int lane = tid & 63;
  const int w    = tid >> 6;
  const int lo   = lane & 15;
  const int hi   = lane >> 4;

  const int qt = blockIdx.x;
  const int z  = blockIdx.y;
  const int b  = z >> 4, h = z & 15;

  const u16* Qb  = qkv + (long)b * SEQ * QKV3 + h * 64;
  const u16* Kb  = Qb + 1024;
  const u16* Vtb = vT + (long)z * 65536;

  bf16x8 q[2][2];
#pragma unroll
  for (int i = 0; i < 2; ++i)
#pragma unroll
    for (int ks = 0; ks < 2; ++ks)
      q[i][ks] = *(const bf16x8*)(Qb + (long)(qt * 128 + w * 32 + i * 16 + lo) * QKV3
                                  + ks * 32 + hi * 8);

  f32x4 po[2][4];
  float m_run[2][4], l_run[2][4];
#pragma unroll
  for (int i = 0; i < 2; ++i)
#pragma unroll
    for (int r = 0; r < 4; ++r) { m_run[i][r] = -1e30f; l_run[i][r] = 0.f; }
#pragma unroll
  for (int i = 0; i < 2; ++i)
#pragma unroll
    for (int nd = 0; nd < 4; ++nd) po[i][nd] = (f32x4){0.f, 0.f, 0.f, 0.f};

  char* Pw = (char*)&Ps[w][0];

  for (int c = 0; c < 8; ++c) {
#pragma unroll
    for (int i = 0; i < 4; ++i) {
      int u = w * 4 + i, g = u & 7, rg = u >> 3;
      gl_lds16(Kb + (long)(c * 128 + rg * 64 + lane) * QKV3 + g * 8, &Ks[g][rg * 64][0]);
    }
#pragma unroll
    for (int i = 0; i < 4; ++i) {
      int kg = w * 4 + i;
      gl_lds16(Vtb + (long)lane * 1024 + c * 128 + kg * 8, &Vs[kg][0][0]);
    }
    __syncthreads();

    f32x4 s[2][8];
#pragma unroll
    for (int i = 0; i < 2; ++i)
#pragma unroll
      for (int jf = 0; jf < 8; ++jf) s[i][jf] = (f32x4){0.f, 0.f, 0.f, 0.f};
#pragma unroll
    for (int jf = 0; jf < 8; ++jf) {
      bf16x8 bk[2];
#pragma unroll
      for (int ks = 0; ks < 2; ++ks)
        bk[ks] = *(const bf16x8*)&Ks[ks * 4 + hi][jf * 16 + lo][0];
#pragma unroll
      for (int i = 0; i < 2; ++i)
#pragma unroll
        for (int ks = 0; ks < 2; ++ks)
          s[i][jf] = __builtin_amdgcn_mfma_f32_16x16x32_bf16(q[i][ks], bk[ks], s[i][jf], 0, 0, 0);
    }

    float scf[2][4];
#pragma unroll
    for (int i = 0; i < 2; ++i) {
#pragma unroll
      for (int r = 0; r < 4; ++r) {
        float rm = -1e30f;
#pragma unroll
        for (int jf = 0; jf < 8; ++jf) {
          s[i][jf][r] *= 0.125f;
          rm = fmaxf(rm, s[i][jf][r]);
        }
#pragma unroll
        for (int o = 1; o < 16; o <<= 1) rm = fmaxf(rm, __shfl_xor(rm, o));
        float mn = fmaxf(m_run[i][r], rm);
        float sc = __expf(m_run[i][r] - mn);
        float rs = 0.f;
#pragma unroll
        for (int jf = 0; jf < 8; ++jf) {
          float e = __expf(s[i][jf][r] - mn);
          s[i][jf][r] = e;
          rs += e;
        }
#pragma unroll
        for (int o = 1; o < 16; o <<= 1) rs += __shfl_xor(rs, o);
        l_run[i][r] = l_run[i][r] * sc + rs;
        m_run[i][r] = mn;
        scf[i][r] = sc;
      }
    }

#pragma unroll
    for (int i = 0; i < 2; ++i)
#pragma unroll
      for (int jf = 0; jf < 8; ++jf)
#pragma unroll
        for (int r = 0; r < 4; ++r) {
          int row = i * 16 + hi * 4 + r;
          int byo = row * 256 + ((((jf * 16 + lo) * 2)) ^ ((row & 7) << 4));
          *(u16*)(Pw + byo) = f2bf(s[i][jf][r]);
        }
#pragma unroll
    for (int i = 0; i < 2; ++i)
#pragma unroll
      for (int nd = 0; nd < 4; ++nd)
#pragma unroll
        for (int r = 0; r < 4; ++r) po[i][nd][r] *= scf[i][r];

    bf16x8 pa[2][4];
#pragma unroll
    for (int i = 0; i < 2; ++i)
#pragma unroll
      for (int ks2 = 0; ks2 < 4; ++ks2) {
        int row = i * 16 + lo;
        int byo = row * 256 + (((ks2 * 32 + hi * 8) * 2) ^ ((row & 7) << 4));
        pa[i][ks2] = *(const bf16x8*)(Pw + byo);
      }
#pragma unroll
    for (int nd = 0; nd < 4; ++nd) {
      bf16x8 bv[4];
#pragma unroll
      for (int ks2 = 0; ks2 < 4; ++ks2)
        bv[ks2] = *(const bf16x8*)&Vs[ks2 * 4 + hi][nd * 16 + lo][0];
#pragma unroll
      for (int i = 0; i < 2; ++i)
#pragma unroll
        for (int ks2 = 0; ks2 < 4; ++ks2)
          po[i][nd] = __builtin_amdgcn_mfma_f32_16x16x32_bf16(pa[i][ks2], bv[ks2], po[i][nd], 0, 0, 0);
    }
    __syncthreads();
  }

#pragma unroll
  for (int i = 0; i < 2; ++i) {
#pragma unroll
    for (int r = 0; r < 4; ++r) {
      float inv = 1.f / l_run[i][r];
      int qrow = qt * 128 + w * 32 + i * 16 + hi * 4 + r;
      u16* dst = ctx + (long)(b * SEQ + qrow) * HID + h * 64;
#pragma unroll
      for (int nd = 0; nd < 4; ++nd)
        dst[nd * 16 + lo] = f2bf(po[i][nd][r] * inv);
    }
  }
}

// ---------------- GEMM: C[m,n] = scale * sum_k A[m,k]*B[n,k] (+resid) ----------------
// A: [M][K] bf16 row-major (lda), B: [N][K] bf16 row-major (ldb).
// EPI: 0 = bf16 out (xscale), 1 = f32 out (xscale), 2 = f32 resid add,
//      3 = fused silu (B rows interleaved gate/up; see r3).
template<int BM, int BN, int EPI>
__global__ __launch_bounds__(256) void gemm_bt(
    const u16* __restrict__ A, const u16* __restrict__ B,
    void* __restrict__ Cv, const float* __restrict__ resid,
    int lda, int ldb, int ldc, int K, float scale, int bdiv,
    long sA1, long sA2, long sB1, long sB2, long sC1, long sC2)
{
  constexpr int FM = BM / 32;
  constexpr int FN = BN / 32;
  __shared__ u16 As[2][BM * 32];
  __shared__ u16 Bs[2][BN * 32];

  const int tid = threadIdx.x;
  const int lane = tid & 63;
  const int wid = tid >> 6;
  const int wm = wid >> 1, wn = wid & 1;

  const int z = blockIdx.z;
  const long offA = (long)(z / bdiv) * sA1 + (long)(z % bdiv) * sA2;
  const long offB = (long)(z / bdiv) * sB1 + (long)(z % bdiv) * sB2;
  const long offC = (long)(z / bdiv) * sC1 + (long)(z % bdiv) * sC2;

  const u16* Ab = A + offA + (long)blockIdx.x * BM * lda;
  const u16* Bb = B + offB + (long)blockIdx.y * BN * ldb;

  auto stage = [&](int buf, int kt) {
    const u16* a = Ab + (long)kt * 32;
    const u16* bsrc = Bb + (long)kt * 32;
#pragma unroll
    for (int i = 0; i < BM / 64; ++i) {
      int row = i * 64 + wid * 16 + (lane >> 2);
      gl_lds16(a + (long)row * lda + (lane & 3) * 8, &As[buf][i * 2048 + wid * 512]);
    }
#pragma unroll
    for (int i = 0; i < BN / 64; ++i) {
      int row = i * 64 + wid * 16 + (lane >> 2);
      gl_lds16(bsrc + (long)row * ldb + (lane & 3) * 8, &Bs[buf][i * 2048 + wid * 512]);
    }
  };

  f32x4 acc[FM][FN];
#pragma unroll
  for (int i = 0; i < FM; ++i)
#pragma unroll
    for (int j = 0; j < FN; ++j) acc[i][j] = (f32x4){0.f, 0.f, 0.f, 0.f};

  int aoff[FM], boff[FN];
#pragma unroll
  for (int i = 0; i < FM; ++i)
    aoff[i] = (wm * (BM / 2) + i * 16 + (lane & 15)) * 32 + (lane >> 4) * 8;
#pragma unroll
  for (int j = 0; j < FN; ++j)
    boff[j] = (wn * (BN / 2) + j * 16 + (lane & 15)) * 32 + (lane >> 4) * 8;

  const int KT = K >> 5;
  stage(0, 0);
  __syncthreads();
  int cur = 0;
  for (int kt = 0; kt < KT; ++kt) {
    if (kt + 1 < KT) stage(cur ^ 1, kt + 1);
    bf16x8 av[FM], bv[FN];
#pragma unroll
    for (int i = 0; i < FM; ++i) av[i] = *(const bf16x8*)&As[cur][aoff[i]];
#pragma unroll
    for (int j = 0; j < FN; ++j) bv[j] = *(const bf16x8*)&Bs[cur][boff[j]];
#pragma unroll
    for (int i = 0; i < FM; ++i)
#pragma unroll
      for (int j = 0; j < FN; ++j)
        acc[i][j] = __builtin_amdgcn_mfma_f32_16x16x32_bf16(av[i], bv[j], acc[i][j], 0, 0, 0);
    __syncthreads();
    cur ^= 1;
  }

  const int r0 = blockIdx.x * BM + wm * (BM / 2) + (lane >> 4) * 4;
  const int c0 = blockIdx.y * BN + wn * (BN / 2) + (lane & 15);
#pragma unroll
  for (int i = 0; i < FM; ++i) {
#pragma unroll
    for (int j = 0; j < FN; ++j) {
      f32x4 v = acc[i][j];
#pragma unroll
      for (int r = 0; r < 4; ++r) {
        if (EPI == 3) {
          float pv = __shfl_xor(v[r], 1);
          if ((lane & 1) == 0) {
            float gf = v[r];
            float res = gf / (1.f + __expf(-gf)) * pv;
            int cc = c0 + j * 16;
            long idx = offC + (long)(r0 + i * 16 + r) * ldc + (cc >> 1);
            ((u16*)Cv)[idx] = f2bf(res);
          }
        } else {
          long idx = offC + (long)(r0 + i * 16 + r) * ldc + (c0 + j * 16);
          if (EPI == 0)       ((u16*)Cv)[idx] = f2bf(v[r] * scale);
          else if (EPI == 1)  ((float*)Cv)[idx] = v[r] * scale;
          else                ((float*)Cv)[idx] = resid[idx] + v[r];
        }
      }
    }
  }
}

// ---------------- gemm_head: 128x256 tile, BK=32, 256 thr, 2 blocks/CU ----------------
// C[m,n] = sum_k A[m,k]*B[n,k].  A:[2048][1024], B:[256*?][1024] bf16, K=1024.
// 4 waves, each covers full 128 M x 64 N (acc 8x4 f32x4 = 128 VGPR).
// Triple-buffered LDS (3 x 24 KB = 72 KB) -> 2 blocks/CU co-resident: the other
// block's MFMAs cover this block's ds_read phases, prologue and f32 epilogue
// (the three costs identified in r4's model).  Prefetch depth 2, counted
// vmcnt(6) at iter end (never drains in steady state).
// Overwrite ledger: stage at iter j targets buf (j+2)%3 = buffer read at iter
// j-1; those reads retired before iter j-1's barrier (MFMA-consumed), stage
// issued after it.  Tile t complete before iter t: vmcnt(6) at end of iter t-1
// forces the oldest 6 (tile t's calls) to land.
template<int EPI>
__global__ __launch_bounds__(256, 2) void gemm_head(
    const u16* __restrict__ A, const u16* __restrict__ B,
    void* __restrict__ Cv, int NB, int ldc)
{
  __shared__ u16 As[3][4][128][8];   // [buf][kg][row][8 bf16]  24 KB
  __shared__ u16 Bs[3][4][256][8];   //                          48 KB

  const int tid  = threadIdx.x;
  const int lane = tid & 63;
  const int w    = tid >> 6;        // 0..3  (N quarter)
  const int lo   = lane & 15;
  const int kg   = lane >> 4;       // 0..3

  const int flat = blockIdx.x;                     // 0 .. 8*NB-1 (nwg % 8 == 0)
  const int swz  = (flat & 7) * NB + (flat >> 3);  // bijective XCD swizzle
  const int bm   = swz & 15;                       // M fastest within XCD chunk
  const int bn   = swz >> 4;

  const u16* Ab = A + (long)bm * 128 * 1024;
  const u16* Bb = B + (long)bn * 256 * 1024;

  // stage K-tile t (A 8KB + B 16KB) into buf: 6 gl_lds16 lines/thread.
  auto stage = [&](int buf, int t) {
#pragma unroll
    for (int i = 0; i < 2; ++i) {            // A: 8 wave-units
      int u = w * 2 + i, g = u & 3, rg = u >> 2;   // rg 0..1
      gl_lds16(Ab + (long)(rg * 64 + lane) * 1024 + t * 32 + g * 8,
               &As[buf][g][rg * 64][0]);
    }
#pragma unroll
    for (int i = 0; i < 4; ++i) {            // B: 16 wave-units
      int u = w * 4 + i, g = u & 3, rg = u >> 2;   // rg 0..3
      gl_lds16(Bb + (long)(rg * 64 + lane) * 1024 + t * 32 + g * 8,
               &Bs[buf][g][rg * 64][0]);
    }
  };

  f32x4 acc[8][4];
#pragma unroll
  for (int f = 0; f < 8; ++f)
#pragma unroll
    for (int n = 0; n < 4; ++n) acc[f][n] = (f32x4){0.f, 0.f, 0.f, 0.f};

#define BAR asm volatile("s_barrier" ::: "memory")

  const int KT = 32;   // K = 1024, BK = 32
  stage(0, 0);
  stage(1, 1);
  asm volatile("s_waitcnt vmcnt(6)" ::: "memory");   // tile0 landed; tile1 in flight
  BAR;

#pragma unroll 1
  for (int t = 0; t < KT; ++t) {
    const int cur = t % 3;
    const bool pf = (t + 2 < KT);
    if (pf) stage((t + 2) % 3, t + 2);

    bf16x8 a[8], b[4];
#pragma unroll
    for (int f = 0; f < 8; ++f)
      a[f] = *(const bf16x8*)&As[cur][kg][f * 16 + lo][0];
#pragma unroll
    for (int n = 0; n < 4; ++n)
      b[n] = *(const bf16x8*)&Bs[cur][kg][w * 64 + n * 16 + lo][0];

    __builtin_amdgcn_s_setprio(1);
#pragma unroll
    for (int f = 0; f < 8; ++f)
#pragma unroll
      for (int n = 0; n < 4; ++n)
        acc[f][n] = __builtin_amdgcn_mfma_f32_16x16x32_bf16(a[f], b[n], acc[f][n], 0, 0, 0);
    __builtin_amdgcn_s_setprio(0);

    if (pf)               asm volatile("s_waitcnt vmcnt(6)" ::: "memory"); // t+1 done
    else if (t + 1 < KT)  asm volatile("s_waitcnt vmcnt(0)" ::: "memory"); // tail drain
    if (t + 1 < KT) BAR;
  }
#undef BAR

  // epilogue: C row = (lane>>4)*4 + reg, col = lane&15 (m89-verified layout)
#pragma unroll
  for (int f = 0; f < 8; ++f) {
    const int r0 = bm * 128 + f * 16 + kg * 4;
#pragma unroll
    for (int n = 0; n < 4; ++n) {
      const int c = bn * 256 + w * 64 + n * 16 + lo;
      f32x4 v = acc[f][n];
#pragma unroll
      for (int r = 0; r < 4; ++r) {
        long idx = (long)(r0 + r) * ldc + c;
        if (EPI == 0) ((u16*)Cv)[idx] = f2bf(v[r]);
        else          ((float*)Cv)[idx] = v[r];
      }
    }
  }
}

extern "C" void kernel_launch(void* const* d_in, const int* in_sizes, int n_in,
                              void* d_out, int out_size, void* d_ws, size_t ws_size,
                              hipStream_t stream)
{
  (void)in_sizes; (void)n_in; (void)out_size; (void)ws_size;
  const int*   ids     = (const int*)d_in[0];
  const float* tok_emb = (const float*)d_in[1];
  const float* pos_emb = (const float*)d_in[2];
  const float* qkv_w   = (const float*)d_in[3];
  const float* o_w     = (const float*)d_in[4];
  const float* gate_w  = (const float*)d_in[5];
  const float* up_w    = (const float*)d_in[6];
  const float* down_w  = (const float*)d_in[7];
  const float* ln1_w   = (const float*)d_in[8];
  const float* ln1_b   = (const float*)d_in[9];
  const float* ln2_w   = (const float*)d_in[10];
  const float* ln2_b   = (const float*)d_in[11];
  const float* lnf_w   = (const float*)d_in[12];
  const float* lnf_b   = (const float*)d_in[13];
  const float* head_w  = (const float*)d_in[14];

  char* ws = (char*)d_ws;
  long off = 0;
  auto alloc = [&](long bytes) { void* p = ws + off; off += (bytes + 1023) & ~1023L; return p; };
  float* h   = (float*)alloc((long)TOK * HID * 4);
  u16*   x   = (u16*)  alloc((long)TOK * HID * 2);
  u16*   qkv = (u16*)  alloc((long)TOK * QKV3 * 2);
  u16*   vT  = (u16*)  alloc(32L * HDIM * SEQ * 2);
  u16*   ctx = (u16*)  alloc((long)TOK * HID * 2);
  u16*   y   = (u16*)  alloc((long)TOK * IPAD * 2);
  u16*   whead = (u16*)alloc((long)VOCAB * HID * 2);   // 65.5 MB; layer weights alias inside
  u16* wq  = whead;                       // 3072*1024
  u16* wo  = wq + 3072 * 1024;            // 1024*1024
  u16* wgu = wo + 1024 * 1024;            // 5632*1024 (interleaved gate/up rows)
  u16* wd  = wgu + 5632 * 1024;           // 1024*2816

  embed_kernel<<<TOK, 256, 0, stream>>>(ids, tok_emb, pos_emb, h);

  for (int l = 0; l < NLAYER; ++l) {
    ln_kernel<<<TOK, 256, 0, stream>>>(h, ln1_w + l * HID, ln1_b + l * HID, x);

    cvt_kernel<<<1536, 256, 0, stream>>>(qkv_w + (long)l * QKV3 * HID, wq, QKV3, HID, HID, 393216L);
    gemm_bt<128, 128, 0><<<dim3(16, 24, 1), 256, 0, stream>>>(
        x, wq, qkv, nullptr, HID, HID, QKV3, HID, 1.f, 1, 0, 0, 0, 0, 0, 0);

    vtrans_kernel<<<1024, 256, 0, stream>>>(qkv, vT);

    // fused flash attention: qkv -> ctx
    attn_kernel<<<dim3(8, 32), 256, 0, stream>>>(qkv, vT, ctx);

    cvt_kernel<<<512, 256, 0, stream>>>(o_w + (long)l * HID * HID, wo, HID, HID, HID, 131072L);
    gemm_bt<64, 128, 2><<<dim3(32, 8, 1), 256, 0, stream>>>(
        ctx, wo, h, h, HID, HID, HID, HID, 1.f, 1, 0, 0, 0, 0, 0, 0);

    ln_kernel<<<TOK, 256, 0, stream>>>(h, ln2_w + l * HID, ln2_b + l * HID, x);

    cvt2i_kernel<<<2816, 256, 0, stream>>>(
        gate_w + (long)l * INTER * HID, up_w + (long)l * INTER * HID, wgu, 720896L);
    gemm_bt<128, 128, 3><<<dim3(16, 44, 1), 256, 0, stream>>>(
        x, wgu, y, nullptr, HID, HID, IPAD, HID, 1.f, 1, 0, 0, 0, 0, 0, 0);

    cvt_kernel<<<1408, 256, 0, stream>>>(down_w + (long)l * HID * INTER, wd, HID, INTER, IPAD, 360448L);
    gemm_bt<64, 128, 2><<<dim3(32, 8, 1), 256, 0, stream>>>(
        y, wd, h, h, IPAD, IPAD, HID, IPAD, 1.f, 1, 0, 0, 0, 0, 0, 0);
  }

  ln_kernel<<<TOK, 256, 0, stream>>>(h, lnf_w, lnf_b, x);
  cvt_kernel<<<16000, 256, 0, stream>>>(head_w, whead, VOCAB, HID, HID, 4096000L);
  gemm_head<1><<<dim3(2000), 256, 0, stream>>>(x, whead, d_out, 250, VOCAB);
}

// Round 6
// 1453.785 us; speedup vs baseline: 1.1088x; 1.1088x over previous
//
#include <hip/hip_runtime.h>

typedef unsigned short u16;
typedef __attribute__((ext_vector_type(8))) short bf16x8;   // 8 bf16 (4 VGPR) MFMA frag
typedef __attribute__((ext_vector_type(8))) unsigned short us8;
typedef __attribute__((ext_vector_type(4))) unsigned short us4;
typedef __attribute__((ext_vector_type(4))) float f32x4;

#define SEQ    1024
#define TOK    2048           // B*S
#define HID    1024
#define NLAYER 6
#define NHEAD  16
#define HDIM   64
#define QKV3   3072
#define INTER  2730
#define IPAD   2816
#define VOCAB  32000
#define LN_EPS 1e-5f

__device__ __forceinline__ u16 f2bf(float f) {
  unsigned u = __float_as_uint(f);
  return (u16)((u + 0x7fffu + ((u >> 16) & 1u)) >> 16);   // RNE
}
__device__ __forceinline__ float bf2f(u16 u) {
  return __uint_as_float(((unsigned)u) << 16);
}

__device__ __forceinline__ void gl_lds16(const void* g, void* l) {
  __builtin_amdgcn_global_load_lds(
      (const __attribute__((address_space(1))) void*)g,
      (__attribute__((address_space(3))) void*)l, 16, 0, 0);
}

// ---------------- embedding: h = tok_emb[id] + pos_emb[s] (f32) ----------------
__global__ __launch_bounds__(256) void embed_kernel(
    const int* __restrict__ ids, const float* __restrict__ tok,
    const float* __restrict__ pos, float* __restrict__ h)
{
  int t = blockIdx.x;
  int s = t & (SEQ - 1);
  int id = ids[t];
  int c = threadIdx.x * 4;
  float4 tv = *(const float4*)(tok + (long)id * HID + c);
  float4 pv = *(const float4*)(pos + (long)s * HID + c);
  float4 o;
  o.x = tv.x + pv.x; o.y = tv.y + pv.y; o.z = tv.z + pv.z; o.w = tv.w + pv.w;
  *(float4*)(h + (long)t * HID + c) = o;
}

// ---------------- layernorm: f32 in -> bf16 out ----------------
__global__ __launch_bounds__(256) void ln_kernel(
    const float* __restrict__ h, const float* __restrict__ w,
    const float* __restrict__ b, u16* __restrict__ out)
{
  int t = blockIdx.x;
  int tid = threadIdx.x;
  int lane = tid & 63, wid = tid >> 6;
  float4 v = *(const float4*)(h + (long)t * HID + tid * 4);
  float s1 = v.x + v.y + v.z + v.w;
  float s2 = v.x * v.x + v.y * v.y + v.z * v.z + v.w * v.w;
#pragma unroll
  for (int o = 32; o > 0; o >>= 1) { s1 += __shfl_down(s1, o); s2 += __shfl_down(s2, o); }
  __shared__ float r1[4], r2[4];
  if (lane == 0) { r1[wid] = s1; r2[wid] = s2; }
  __syncthreads();
  float t1 = r1[0] + r1[1] + r1[2] + r1[3];
  float t2 = r2[0] + r2[1] + r2[2] + r2[3];
  float mu = t1 * (1.f / HID);
  float var = t2 * (1.f / HID) - mu * mu;
  float rs = rsqrtf(var + LN_EPS);
  float4 wv = *(const float4*)(w + tid * 4);
  float4 bv = *(const float4*)(b + tid * 4);
  us4 o4;
  o4[0] = f2bf((v.x - mu) * rs * wv.x + bv.x);
  o4[1] = f2bf((v.y - mu) * rs * wv.y + bv.y);
  o4[2] = f2bf((v.z - mu) * rs * wv.z + bv.z);
  o4[3] = f2bf((v.w - mu) * rs * wv.w + bv.w);
  *(us4*)(out + (long)t * HID + tid * 4) = o4;
}

// ---------------- f32 -> bf16 weight convert with zero padding ----------------
__global__ __launch_bounds__(256) void cvt_kernel(
    const float* __restrict__ src, u16* __restrict__ dst,
    int N, int K, int Kpad, long total8)
{
  long i = (long)blockIdx.x * 256 + threadIdx.x;
  if (i >= total8) return;
  int kp8 = Kpad >> 3;
  int n = (int)(i / kp8);
  int kc = (int)(i % kp8);
  us8 o;
#pragma unroll
  for (int j = 0; j < 8; ++j) {
    int k = kc * 8 + j;
    float v = (n < N && k < K) ? src[(long)n * K + k] : 0.f;
    o[j] = f2bf(v);
  }
  *(us8*)(dst + i * 8) = o;
}

// ---- fused per-layer weight convert: wq | wo | wgu(interleaved) | wd ----
// chunk ranges (us8 units): wq 393216, wo 131072, wgu 720896, wd 360448.
__global__ __launch_bounds__(256) void cvt_layer_kernel(
    const float* __restrict__ qkv_w, const float* __restrict__ o_w,
    const float* __restrict__ gate, const float* __restrict__ up,
    const float* __restrict__ down,
    u16* __restrict__ wq, u16* __restrict__ wo,
    u16* __restrict__ wgu, u16* __restrict__ wd)
{
  long i = (long)blockIdx.x * 256 + threadIdx.x;   // 0 .. 1605631
  us8 o;
  if (i < 393216L) {                         // wq: 3072x1024, no pad
    const float* s = qkv_w + i * 8;
#pragma unroll
    for (int j = 0; j < 8; ++j) o[j] = f2bf(s[j]);
    *(us8*)(wq + i * 8) = o;
  } else if (i < 524288L) {                  // wo: 1024x1024, no pad
    long i2 = i - 393216L;
    const float* s = o_w + i2 * 8;
#pragma unroll
    for (int j = 0; j < 8; ++j) o[j] = f2bf(s[j]);
    *(us8*)(wo + i2 * 8) = o;
  } else if (i < 1245184L) {                 // wgu: 5632 interleaved rows x 1024
    long i3 = i - 524288L;
    int n = (int)(i3 >> 7);
    int kc = (int)(i3 & 127);
    int g = n >> 1;
    const float* s = (n & 1) ? up : gate;
#pragma unroll
    for (int j = 0; j < 8; ++j) {
      int k = kc * 8 + j;
      o[j] = f2bf((g < INTER) ? s[(long)g * HID + k] : 0.f);
    }
    *(us8*)(wgu + i3 * 8) = o;
  } else {                                   // wd: 1024 x (2730 -> pad 2816)
    long i4 = i - 1245184L;
    int n = (int)(i4 / 352);
    int kc = (int)(i4 % 352);
#pragma unroll
    for (int j = 0; j < 8; ++j) {
      int k = kc * 8 + j;
      o[j] = f2bf((k < INTER) ? down[(long)n * INTER + k] : 0.f);
    }
    *(us8*)(wd + i4 * 8) = o;
  }
}

// ---------------- V transpose: vT[z][d][k] = qkv[b][k][2048 + h*64 + d] ----------------
__global__ __launch_bounds__(256) void vtrans_kernel(
    const u16* __restrict__ qkv, u16* __restrict__ vT)
{
  int gid = blockIdx.x * 256 + threadIdx.x;     // 32*64*128 total
  int d  = gid & 63;
  int kc = (gid >> 6) & 127;
  int z  = gid >> 13;                           // b*16+h
  int b = z >> 4, hh = z & 15;
  const u16* src = qkv + (long)b * SEQ * QKV3 + 2048 + hh * 64 + d;
  us8 v;
#pragma unroll
  for (int j = 0; j < 8; ++j) v[j] = src[(long)(kc * 8 + j) * QKV3];
  *(us8*)(vT + (long)z * 65536 + (long)d * 1024 + kc * 8) = v;
}

// ---------------- fused flash attention (see r4; r6: z-major flat grid) ----------------
// Flat grid 256: z = id & 31, qt = id >> 5.  All 8 q-tile blocks of one z have
// id ≡ z (mod 8) -> same XCD -> K/V of that head hit one L2 instead of 8.
__global__ __launch_bounds__(256, 2) void attn_kernel(
    const u16* __restrict__ qkv, const u16* __restrict__ vT,
    u16* __restrict__ ctx)
{
  __shared__ u16 Ks[8][128][8];     // [d-grp][kseq][8d]  16 KB
  __shared__ u16 Vs[16][64][8];     // [k-grp][d][8k]     16 KB
  __shared__ u16 Ps[4][32 * 128];   // per-wave P tile    32 KB

  const int tid  = threadIdx.x;
  const int lane = tid & 63;
  const int w    = tid >> 6;
  const int lo   = lane & 15;
  const int hi   = lane >> 4;

  const int z  = blockIdx.x & 31;
  const int qt = blockIdx.x >> 5;
  const int b  = z >> 4, h = z & 15;

  const u16* Qb  = qkv + (long)b * SEQ * QKV3 + h * 64;
  const u16* Kb  = Qb + 1024;
  const u16* Vtb = vT + (long)z * 65536;

  bf16x8 q[2][2];
#pragma unroll
  for (int i = 0; i < 2; ++i)
#pragma unroll
    for (int ks = 0; ks < 2; ++ks)
      q[i][ks] = *(const bf16x8*)(Qb + (long)(qt * 128 + w * 32 + i * 16 + lo) * QKV3
                                  + ks * 32 + hi * 8);

  f32x4 po[2][4];
  float m_run[2][4], l_run[2][4];
#pragma unroll
  for (int i = 0; i < 2; ++i)
#pragma unroll
    for (int r = 0; r < 4; ++r) { m_run[i][r] = -1e30f; l_run[i][r] = 0.f; }
#pragma unroll
  for (int i = 0; i < 2; ++i)
#pragma unroll
    for (int nd = 0; nd < 4; ++nd) po[i][nd] = (f32x4){0.f, 0.f, 0.f, 0.f};

  char* Pw = (char*)&Ps[w][0];

  for (int c = 0; c < 8; ++c) {
#pragma unroll
    for (int i = 0; i < 4; ++i) {
      int u = w * 4 + i, g = u & 7, rg = u >> 3;
      gl_lds16(Kb + (long)(c * 128 + rg * 64 + lane) * QKV3 + g * 8, &Ks[g][rg * 64][0]);
    }
#pragma unroll
    for (int i = 0; i < 4; ++i) {
      int kg = w * 4 + i;
      gl_lds16(Vtb + (long)lane * 1024 + c * 128 + kg * 8, &Vs[kg][0][0]);
    }
    __syncthreads();

    f32x4 s[2][8];
#pragma unroll
    for (int i = 0; i < 2; ++i)
#pragma unroll
      for (int jf = 0; jf < 8; ++jf) s[i][jf] = (f32x4){0.f, 0.f, 0.f, 0.f};
#pragma unroll
    for (int jf = 0; jf < 8; ++jf) {
      bf16x8 bk[2];
#pragma unroll
      for (int ks = 0; ks < 2; ++ks)
        bk[ks] = *(const bf16x8*)&Ks[ks * 4 + hi][jf * 16 + lo][0];
#pragma unroll
      for (int i = 0; i < 2; ++i)
#pragma unroll
        for (int ks = 0; ks < 2; ++ks)
          s[i][jf] = __builtin_amdgcn_mfma_f32_16x16x32_bf16(q[i][ks], bk[ks], s[i][jf], 0, 0, 0);
    }

    float scf[2][4];
#pragma unroll
    for (int i = 0; i < 2; ++i) {
#pragma unroll
      for (int r = 0; r < 4; ++r) {
        float rm = -1e30f;
#pragma unroll
        for (int jf = 0; jf < 8; ++jf) {
          s[i][jf][r] *= 0.125f;
          rm = fmaxf(rm, s[i][jf][r]);
        }
#pragma unroll
        for (int o = 1; o < 16; o <<= 1) rm = fmaxf(rm, __shfl_xor(rm, o));
        float mn = fmaxf(m_run[i][r], rm);
        float sc = __expf(m_run[i][r] - mn);
        float rs = 0.f;
#pragma unroll
        for (int jf = 0; jf < 8; ++jf) {
          float e = __expf(s[i][jf][r] - mn);
          s[i][jf][r] = e;
          rs += e;
        }
#pragma unroll
        for (int o = 1; o < 16; o <<= 1) rs += __shfl_xor(rs, o);
        l_run[i][r] = l_run[i][r] * sc + rs;
        m_run[i][r] = mn;
        scf[i][r] = sc;
      }
    }

#pragma unroll
    for (int i = 0; i < 2; ++i)
#pragma unroll
      for (int jf = 0; jf < 8; ++jf)
#pragma unroll
        for (int r = 0; r < 4; ++r) {
          int row = i * 16 + hi * 4 + r;
          int byo = row * 256 + ((((jf * 16 + lo) * 2)) ^ ((row & 7) << 4));
          *(u16*)(Pw + byo) = f2bf(s[i][jf][r]);
        }
#pragma unroll
    for (int i = 0; i < 2; ++i)
#pragma unroll
      for (int nd = 0; nd < 4; ++nd)
#pragma unroll
        for (int r = 0; r < 4; ++r) po[i][nd][r] *= scf[i][r];

    bf16x8 pa[2][4];
#pragma unroll
    for (int i = 0; i < 2; ++i)
#pragma unroll
      for (int ks2 = 0; ks2 < 4; ++ks2) {
        int row = i * 16 + lo;
        int byo = row * 256 + (((ks2 * 32 + hi * 8) * 2) ^ ((row & 7) << 4));
        pa[i][ks2] = *(const bf16x8*)(Pw + byo);
      }
#pragma unroll
    for (int nd = 0; nd < 4; ++nd) {
      bf16x8 bv[4];
#pragma unroll
      for (int ks2 = 0; ks2 < 4; ++ks2)
        bv[ks2] = *(const bf16x8*)&Vs[ks2 * 4 + hi][nd * 16 + lo][0];
#pragma unroll
      for (int i = 0; i < 2; ++i)
#pragma unroll
        for (int ks2 = 0; ks2 < 4; ++ks2)
          po[i][nd] = __builtin_amdgcn_mfma_f32_16x16x32_bf16(pa[i][ks2], bv[ks2], po[i][nd], 0, 0, 0);
    }
    __syncthreads();
  }

#pragma unroll
  for (int i = 0; i < 2; ++i) {
#pragma unroll
    for (int r = 0; r < 4; ++r) {
      float inv = 1.f / l_run[i][r];
      int qrow = qt * 128 + w * 32 + i * 16 + hi * 4 + r;
      u16* dst = ctx + (long)(b * SEQ + qrow) * HID + h * 64;
#pragma unroll
      for (int nd = 0; nd < 4; ++nd)
        dst[nd * 16 + lo] = f2bf(po[i][nd][r] * inv);
    }
  }
}

// ---------------- GEMM: C[m,n] = scale * sum_k A[m,k]*B[n,k] (+resid) ----------------
// A: [M][K] bf16 row-major (lda), B: [N][K] bf16 row-major (ldb).
// EPI: 0 = bf16 out (xscale), 1 = f32 out (xscale), 2 = f32 resid add,
//      3 = fused silu (B rows interleaved gate/up; see r3).
template<int BM, int BN, int EPI>
__global__ __launch_bounds__(256) void gemm_bt(
    const u16* __restrict__ A, const u16* __restrict__ B,
    void* __restrict__ Cv, const float* __restrict__ resid,
    int lda, int ldb, int ldc, int K, float scale, int bdiv,
    long sA1, long sA2, long sB1, long sB2, long sC1, long sC2)
{
  constexpr int FM = BM / 32;
  constexpr int FN = BN / 32;
  __shared__ u16 As[2][BM * 32];
  __shared__ u16 Bs[2][BN * 32];

  const int tid = threadIdx.x;
  const int lane = tid & 63;
  const int wid = tid >> 6;
  const int wm = wid >> 1, wn = wid & 1;

  const int z = blockIdx.z;
  const long offA = (long)(z / bdiv) * sA1 + (long)(z % bdiv) * sA2;
  const long offB = (long)(z / bdiv) * sB1 + (long)(z % bdiv) * sB2;
  const long offC = (long)(z / bdiv) * sC1 + (long)(z % bdiv) * sC2;

  const u16* Ab = A + offA + (long)blockIdx.x * BM * lda;
  const u16* Bb = B + offB + (long)blockIdx.y * BN * ldb;

  auto stage = [&](int buf, int kt) {
    const u16* a = Ab + (long)kt * 32;
    const u16* bsrc = Bb + (long)kt * 32;
#pragma unroll
    for (int i = 0; i < BM / 64; ++i) {
      int row = i * 64 + wid * 16 + (lane >> 2);
      gl_lds16(a + (long)row * lda + (lane & 3) * 8, &As[buf][i * 2048 + wid * 512]);
    }
#pragma unroll
    for (int i = 0; i < BN / 64; ++i) {
      int row = i * 64 + wid * 16 + (lane >> 2);
      gl_lds16(bsrc + (long)row * ldb + (lane & 3) * 8, &Bs[buf][i * 2048 + wid * 512]);
    }
  };

  f32x4 acc[FM][FN];
#pragma unroll
  for (int i = 0; i < FM; ++i)
#pragma unroll
    for (int j = 0; j < FN; ++j) acc[i][j] = (f32x4){0.f, 0.f, 0.f, 0.f};

  int aoff[FM], boff[FN];
#pragma unroll
  for (int i = 0; i < FM; ++i)
    aoff[i] = (wm * (BM / 2) + i * 16 + (lane & 15)) * 32 + (lane >> 4) * 8;
#pragma unroll
  for (int j = 0; j < FN; ++j)
    boff[j] = (wn * (BN / 2) + j * 16 + (lane & 15)) * 32 + (lane >> 4) * 8;

  const int KT = K >> 5;
  stage(0, 0);
  __syncthreads();
  int cur = 0;
  for (int kt = 0; kt < KT; ++kt) {
    if (kt + 1 < KT) stage(cur ^ 1, kt + 1);
    bf16x8 av[FM], bv[FN];
#pragma unroll
    for (int i = 0; i < FM; ++i) av[i] = *(const bf16x8*)&As[cur][aoff[i]];
#pragma unroll
    for (int j = 0; j < FN; ++j) bv[j] = *(const bf16x8*)&Bs[cur][boff[j]];
#pragma unroll
    for (int i = 0; i < FM; ++i)
#pragma unroll
      for (int j = 0; j < FN; ++j)
        acc[i][j] = __builtin_amdgcn_mfma_f32_16x16x32_bf16(av[i], bv[j], acc[i][j], 0, 0, 0);
    __syncthreads();
    cur ^= 1;
  }

  const int r0 = blockIdx.x * BM + wm * (BM / 2) + (lane >> 4) * 4;
  const int c0 = blockIdx.y * BN + wn * (BN / 2) + (lane & 15);
#pragma unroll
  for (int i = 0; i < FM; ++i) {
#pragma unroll
    for (int j = 0; j < FN; ++j) {
      f32x4 v = acc[i][j];
#pragma unroll
      for (int r = 0; r < 4; ++r) {
        if (EPI == 3) {
          float pv = __shfl_xor(v[r], 1);
          if ((lane & 1) == 0) {
            float gf = v[r];
            float res = gf / (1.f + __expf(-gf)) * pv;
            int cc = c0 + j * 16;
            long idx = offC + (long)(r0 + i * 16 + r) * ldc + (cc >> 1);
            ((u16*)Cv)[idx] = f2bf(res);
          }
        } else {
          long idx = offC + (long)(r0 + i * 16 + r) * ldc + (c0 + j * 16);
          if (EPI == 0)       ((u16*)Cv)[idx] = f2bf(v[r] * scale);
          else if (EPI == 1)  ((float*)Cv)[idx] = v[r] * scale;
          else                ((float*)Cv)[idx] = resid[idx] + v[r];
        }
      }
    }
  }
}

// ---------------- gemm256: 256x256 tile, BK=64, 4 merged phases/iter (r2-r4, 190-196us) ----------------
template<int EPI>
__global__ __launch_bounds__(512, 1) void gemm256(
    const u16* __restrict__ A, const u16* __restrict__ B,
    void* __restrict__ Cv, int NB, int ldc)
{
  __shared__ u16 lds[2][2][2][8][128][8];   // [dbuf][mat][half][kg][row][8] = 128 KiB

  const int tid  = threadIdx.x;
  const int lane = tid & 63;
  const int w    = tid >> 6;
  const int wm   = w >> 2;
  const int wn   = w & 3;
  const int arow = lane & 15;
  const int kg   = lane >> 4;

  const int flat = blockIdx.x;
  const int swz  = (flat & 7) * NB + (flat >> 3);
  const int bm   = swz & 7;
  const int bn   = swz >> 3;

  const u16* Ab = A + (long)bm * 256 * 1024;
  const u16* Bb = B + (long)bn * 256 * 1024;

  auto stage = [&](int mat, int d, int half, int t) {
#pragma unroll
    for (int i = 0; i < 2; ++i) {
      const int u  = w * 2 + i;
      const int g  = u & 7;
      const int rg = u >> 3;
      const u16* src = (mat == 0 ? Ab : Bb)
                     + (long)(half * 128 + rg * 64 + lane) * 1024 + t * 64 + g * 8;
      gl_lds16(src, &lds[d][mat][half][g][rg * 64][0]);
    }
  };

  f32x4 acc[2][2][4][2];
#pragma unroll
  for (int qm = 0; qm < 2; ++qm)
#pragma unroll
    for (int qn = 0; qn < 2; ++qn)
#pragma unroll
      for (int f = 0; f < 4; ++f)
#pragma unroll
        for (int n = 0; n < 2; ++n) acc[qm][qn][f][n] = (f32x4){0.f, 0.f, 0.f, 0.f};

  bf16x8 a[4][2];
  bf16x8 b[2][2][2];

  auto rdA = [&](int d, int qm) {
#pragma unroll
    for (int f = 0; f < 4; ++f)
#pragma unroll
      for (int ks = 0; ks < 2; ++ks)
        a[f][ks] = *(const bf16x8*)&lds[d][0][wm][ks * 4 + kg][qm * 64 + f * 16 + arow][0];
  };
  auto rdB = [&](int d, int qn) {
#pragma unroll
    for (int n = 0; n < 2; ++n)
#pragma unroll
      for (int ks = 0; ks < 2; ++ks)
        b[qn][n][ks] = *(const bf16x8*)&lds[d][1][wn >> 1][ks * 4 + kg]
                                          [(wn & 1) * 64 + qn * 32 + n * 16 + arow][0];
  };
  auto mm = [&](int qm, int qn) {
#pragma unroll
    for (int f = 0; f < 4; ++f)
#pragma unroll
      for (int n = 0; n < 2; ++n)
#pragma unroll
        for (int ks = 0; ks < 2; ++ks)
          acc[qm][qn][f][n] = __builtin_amdgcn_mfma_f32_16x16x32_bf16(
              a[f][ks], b[qn][n][ks], acc[qm][qn][f][n], 0, 0, 0);
  };

#define BAR asm volatile("s_barrier" ::: "memory")
#define PRIO1 __builtin_amdgcn_s_setprio(1)
#define PRIO0 __builtin_amdgcn_s_setprio(0)

  stage(1, 0, 0, 0);
  stage(0, 0, 0, 0);
  stage(0, 0, 1, 0);
  stage(1, 0, 1, 0);
  stage(1, 1, 0, 1);
  stage(0, 1, 0, 1);
  asm volatile("s_waitcnt vmcnt(4)" ::: "memory");
  BAR;

  const int iters = 8;
#pragma unroll 1
  for (int it = 0; it < iters; ++it) {
    const int T = 2 * it;
    const bool pf = (it + 1 < iters);
    rdA(0, 0); rdB(0, 0); rdB(0, 1);
    stage(0, 1, 1, T + 1);
    stage(1, 1, 1, T + 1);
    BAR; PRIO1; mm(0, 0); mm(0, 1); PRIO0; BAR;
    rdA(0, 1);
    if (pf) { stage(1, 0, 0, T + 2);
              stage(0, 0, 0, T + 2); }
    BAR; PRIO1; mm(1, 0); mm(1, 1); PRIO0;
    if (pf) asm volatile("s_waitcnt vmcnt(4)" ::: "memory");
    else    asm volatile("s_waitcnt vmcnt(0)" ::: "memory");
    BAR;
    rdA(1, 0); rdB(1, 0); rdB(1, 1);
    if (pf) { stage(0, 0, 1, T + 2);
              stage(1, 0, 1, T + 2); }
    BAR; PRIO1; mm(0, 0); mm(0, 1); PRIO0; BAR;
    rdA(1, 1);
    if (pf) { stage(1, 1, 0, T + 3);
              stage(0, 1, 0, T + 3); }
    BAR; PRIO1; mm(1, 0); mm(1, 1); PRIO0;
    if (pf) asm volatile("s_waitcnt vmcnt(4)" ::: "memory");
    BAR;
  }
#undef BAR
#undef PRIO1
#undef PRIO0

#pragma unroll
  for (int qm = 0; qm < 2; ++qm) {
#pragma unroll
    for (int qn = 0; qn < 2; ++qn) {
#pragma unroll
      for (int f = 0; f < 4; ++f) {
        const int r0 = bm * 256 + wm * 128 + qm * 64 + f * 16 + kg * 4;
#pragma unroll
        for (int n = 0; n < 2; ++n) {
          const int c = bn * 256 + wn * 64 + qn * 32 + n * 16 + arow;
          f32x4 v = acc[qm][qn][f][n];
#pragma unroll
          for (int r = 0; r < 4; ++r) {
            long idx = (long)(r0 + r) * ldc + c;
            if (EPI == 0) ((u16*)Cv)[idx] = f2bf(v[r]);
            else          ((float*)Cv)[idx] = v[r];
          }
        }
      }
    }
  }
}

extern "C" void kernel_launch(void* const* d_in, const int* in_sizes, int n_in,
                              void* d_out, int out_size, void* d_ws, size_t ws_size,
                              hipStream_t stream)
{
  (void)in_sizes; (void)n_in; (void)out_size; (void)ws_size;
  const int*   ids     = (const int*)d_in[0];
  const float* tok_emb = (const float*)d_in[1];
  const float* pos_emb = (const float*)d_in[2];
  const float* qkv_w   = (const float*)d_in[3];
  const float* o_w     = (const float*)d_in[4];
  const float* gate_w  = (const float*)d_in[5];
  const float* up_w    = (const float*)d_in[6];
  const float* down_w  = (const float*)d_in[7];
  const float* ln1_w   = (const float*)d_in[8];
  const float* ln1_b   = (const float*)d_in[9];
  const float* ln2_w   = (const float*)d_in[10];
  const float* ln2_b   = (const float*)d_in[11];
  const float* lnf_w   = (const float*)d_in[12];
  const float* lnf_b   = (const float*)d_in[13];
  const float* head_w  = (const float*)d_in[14];

  char* ws = (char*)d_ws;
  long off = 0;
  auto alloc = [&](long bytes) { void* p = ws + off; off += (bytes + 1023) & ~1023L; return p; };
  float* h   = (float*)alloc((long)TOK * HID * 4);
  u16*   x   = (u16*)  alloc((long)TOK * HID * 2);
  u16*   qkv = (u16*)  alloc((long)TOK * QKV3 * 2);
  u16*   vT  = (u16*)  alloc(32L * HDIM * SEQ * 2);
  u16*   ctx = (u16*)  alloc((long)TOK * HID * 2);
  u16*   y   = (u16*)  alloc((long)TOK * IPAD * 2);
  u16*   whead = (u16*)alloc((long)VOCAB * HID * 2);   // 65.5 MB; layer weights alias inside
  u16* wq  = whead;                       // 3072*1024
  u16* wo  = wq + 3072 * 1024;            // 1024*1024
  u16* wgu = wo + 1024 * 1024;            // 5632*1024 (interleaved gate/up rows)
  u16* wd  = wgu + 5632 * 1024;           // 1024*2816

  embed_kernel<<<TOK, 256, 0, stream>>>(ids, tok_emb, pos_emb, h);

  for (int l = 0; l < NLAYER; ++l) {
    // all four weight tensors of this layer in one dispatch
    cvt_layer_kernel<<<6272, 256, 0, stream>>>(
        qkv_w + (long)l * QKV3 * HID, o_w + (long)l * HID * HID,
        gate_w + (long)l * INTER * HID, up_w + (long)l * INTER * HID,
        down_w + (long)l * HID * INTER, wq, wo, wgu, wd);

    ln_kernel<<<TOK, 256, 0, stream>>>(h, ln1_w + l * HID, ln1_b + l * HID, x);

    gemm_bt<128, 128, 0><<<dim3(16, 24, 1), 256, 0, stream>>>(
        x, wq, qkv, nullptr, HID, HID, QKV3, HID, 1.f, 1, 0, 0, 0, 0, 0, 0);

    vtrans_kernel<<<1024, 256, 0, stream>>>(qkv, vT);

    // fused flash attention: qkv -> ctx   (z-major flat grid for XCD locality)
    attn_kernel<<<dim3(256), 256, 0, stream>>>(qkv, vT, ctx);

    gemm_bt<64, 128, 2><<<dim3(32, 8, 1), 256, 0, stream>>>(
        ctx, wo, h, h, HID, HID, HID, HID, 1.f, 1, 0, 0, 0, 0, 0, 0);

    ln_kernel<<<TOK, 256, 0, stream>>>(h, ln2_w + l * HID, ln2_b + l * HID, x);

    gemm_bt<128, 128, 3><<<dim3(16, 44, 1), 256, 0, stream>>>(
        x, wgu, y, nullptr, HID, HID, IPAD, HID, 1.f, 1, 0, 0, 0, 0, 0, 0);

    gemm_bt<64, 128, 2><<<dim3(32, 8, 1), 256, 0, stream>>>(
        y, wd, h, h, IPAD, IPAD, HID, IPAD, 1.f, 1, 0, 0, 0, 0, 0, 0);
  }

  ln_kernel<<<TOK, 256, 0, stream>>>(h, lnf_w, lnf_b, x);
  cvt_kernel<<<16000, 256, 0, stream>>>(head_w, whead, VOCAB, HID, HID, 4096000L);
  gemm256<1><<<dim3(1000), 512, 0, stream>>>(x, whead, d_out, 125, VOCAB);
}